// Round 1
// baseline (144.925 us; speedup 1.0000x reference)
//
#include <hip/hip_runtime.h>
#include <hip/hip_bf16.h>

// VQ-VAE quantization forward for MI355X (gfx950).
// outputs (concat in d_out, fp32): quantized_ [16*4096*256], commitment_loss [1], perplexity [1]
//
// v2: occupancy + stage pipelining.
//   - 1024 blocks x 512 threads; each block owns 64 rows. Wave w: row tile (w&3)*16,
//     code half w>>2 (two waves share rows, split the 512 codes; LDS combine at end).
//   - Codebook visited in 16 stages of 32 codes, DOUBLE-BUFFERED 16 KB LDS buffers:
//     issue global_load_lds for stage s+1 before computing stage s (one barrier/stage),
//     so the L2 fetch hides under MFMA.
//   - LDS ~38.2 KB/block -> 4 blocks/CU = 32 waves/CU (was 2 blocks, 70.6 KB).

typedef _Float16 half8_t __attribute__((ext_vector_type(8)));
typedef _Float16 half4_t __attribute__((ext_vector_type(4)));
typedef float f32x4 __attribute__((ext_vector_type(4)));

static constexpr int kRows = 65536;   // N*T
static constexpr int kD = 256;
static constexpr int kM = 512;
static constexpr int kBM = 64;        // rows per block

typedef const unsigned int __attribute__((address_space(1)))* gas_t;
typedef unsigned int __attribute__((address_space(3)))* las_t;

// ---------------- prep: normalize codebook -> fp16 in MFMA B-fragment order, bias, zero hist/loss --------
// swz layout (halves): [group g=c>>4][ko=k>>5][lane = qd*16 + (c&15)][j = k&7], qd=(k>>3)&3.
// A wave's read at lane*16B yields B[k=ko*32+qd*8+j][n=g*16+ln] as mfma_f32_16x16x32_f16 wants.
__global__ void vq_prep(const float* __restrict__ emb, _Float16* __restrict__ swz,
                        float* __restrict__ bias, unsigned int* __restrict__ hist,
                        float* __restrict__ loss) {
    const int j = blockIdx.x;       // code row, 512 blocks
    const int lane = threadIdx.x;   // 64 threads = 1 wave
    float4 v = ((const float4*)(emb + j * kD))[lane];
    float ss = v.x * v.x + v.y * v.y + v.z * v.z + v.w * v.w;
    #pragma unroll
    for (int off = 32; off > 0; off >>= 1) ss += __shfl_xor(ss, off);
    const float scale = 1.0f / (sqrtf(ss) + 1e-4f);
    if (lane == 0) bias[j] = 0.5f * ss * scale * scale;
    half4_t h;
    h[0] = (_Float16)(v.x * scale);
    h[1] = (_Float16)(v.y * scale);
    h[2] = (_Float16)(v.z * scale);
    h[3] = (_Float16)(v.w * scale);
    const int k0 = lane * 4;        // this lane covers k0..k0+3 (within one 8-half j-chunk)
    const int ko = k0 >> 5;
    const int qd = (k0 >> 3) & 3;
    const int jj = k0 & 7;          // 0 or 4
    const int off_h = (j >> 4) * 4096 + ko * 512 + (qd * 16 + (j & 15)) * 8 + jj;
    *(half4_t*)(swz + off_h) = h;
    if (j == 0) {
        for (int b = lane; b < kM; b += 64) hist[b] = 0u;
        if (lane == 0) loss[0] = 0.0f;
    }
}

// ---------------- main: persistent A-frags, double-buffered 32-code stages, argmax + gather + loss ------
__global__ __launch_bounds__(512, 8) void vq_main(
    const float* __restrict__ x, const float* __restrict__ emb,
    const _Float16* __restrict__ bswz, const float* __restrict__ bias,
    unsigned int* __restrict__ hist, float* __restrict__ loss_accum,
    float* __restrict__ out) {
    __shared__ _Float16 bb0[32 * kD];       // 16 KB: stage buffer 0 (one 32-code stage)
    __shared__ _Float16 bb1[32 * kD];       // 16 KB: stage buffer 1
    __shared__ float lbias[kM];             // 2048 B
    __shared__ unsigned int lhist[kM];      // 2048 B
    __shared__ int lidx[kBM];               // 256 B
    __shared__ float lbv[kBM * 2];          // 512 B: per-row best value, per code-half
    __shared__ int lbi[kBM * 2];            // 512 B: per-row best index, per code-half
    __shared__ float lred[8];

    const int t = threadIdx.x;              // 0..511, 8 waves
    const int row0 = blockIdx.x * kBM;
    const int wave = t >> 6;
    const int lane = t & 63;
    const int qd = lane >> 4;               // quad 0..3
    const int ln = lane & 15;
    const int m0 = (wave & 3) * 16;         // wave's local row base (rows m0..m0+15)
    const int h = wave >> 2;                // code half: sub-block 0 or 1 of each stage

    lhist[t] = 0u;
    lbias[t] = bias[t];

    // issue stage 0 (codes 0..31 = swz groups 0,1) into bb0: 512 thr x 2 x 16 B direct-to-LDS
    {
        const _Float16* src = bswz + t * 8;
        __builtin_amdgcn_global_load_lds((gas_t)(const void*)(src),
                                         (las_t)(void*)(bb0 + t * 8), 16, 0, 0);
        __builtin_amdgcn_global_load_lds((gas_t)(const void*)(src + 4096),
                                         (las_t)(void*)(bb0 + t * 8 + 4096), 16, 0, 0);
    }

    // A fragments, loaded ONCE: A[m=ln][k=ko*32+qd*8+j], fp32->fp16, resident in 32 VGPRs
    half8_t a[8];
    {
        const float* xr = x + (size_t)(row0 + m0 + ln) * kD + qd * 8;
        #pragma unroll
        for (int ko = 0; ko < 8; ++ko) {
            const float4 v0 = *(const float4*)(xr + ko * 32);
            const float4 v1 = *(const float4*)(xr + ko * 32 + 4);
            half8_t hh;
            hh[0] = (_Float16)v0.x; hh[1] = (_Float16)v0.y;
            hh[2] = (_Float16)v0.z; hh[3] = (_Float16)v0.w;
            hh[4] = (_Float16)v1.x; hh[5] = (_Float16)v1.y;
            hh[6] = (_Float16)v1.z; hh[7] = (_Float16)v1.w;
            a[ko] = hh;
        }
    }
    __syncthreads();   // stage 0 + lbias/lhist + A ready (compiler drains vmcnt here)

    float bv[4] = {-1e30f, -1e30f, -1e30f, -1e30f};
    int bi[4] = {0, 0, 0, 0};

    // stage s covers codes s*32..s*32+31 = swz groups 2s,2s+1 at halves offset s*8192
    auto issue = [&](int s, _Float16* dst) {
        const _Float16* src = bswz + (size_t)s * 8192 + t * 8;
        __builtin_amdgcn_global_load_lds((gas_t)(const void*)(src),
                                         (las_t)(void*)(dst + t * 8), 16, 0, 0);
        __builtin_amdgcn_global_load_lds((gas_t)(const void*)(src + 4096),
                                         (las_t)(void*)(dst + t * 8 + 4096), 16, 0, 0);
    };
    // score = x.e_norm - 0.5*||e_norm||^2 (bias in acc init); this wave handles its code half
    auto compute = [&](int s, const _Float16* buf) {
        const int c = s * 32 + h * 16 + ln;
        const float bbias = lbias[c];
        f32x4 acc = {-bbias, -bbias, -bbias, -bbias};
        const half8_t* bp = (const half8_t*)buf + h * 512 + lane;
        #pragma unroll
        for (int ko = 0; ko < 8; ++ko)
            acc = __builtin_amdgcn_mfma_f32_16x16x32_f16(a[ko], bp[ko * 64], acc, 0, 0, 0);
        #pragma unroll
        for (int r = 0; r < 4; ++r)   // D[m][n]: n=ln, m=qd*4+r; lowest-index tie-break
            if (acc[r] > bv[r] || (acc[r] == bv[r] && c < bi[r])) { bv[r] = acc[r]; bi[r] = c; }
    };

    #pragma unroll 1
    for (int s = 0; s < 16; s += 2) {
        issue(s + 1, bb1);              // prefetch next stage; completes at barrier below
        compute(s, bb0);
        __syncthreads();
        if (s + 2 < 16) issue(s + 2, bb0);
        compute(s + 1, bb1);
        __syncthreads();
    }

    // reduce over the 16 lanes of each quad (same rows, different code subsets within half)
    #pragma unroll
    for (int r = 0; r < 4; ++r) {
        #pragma unroll
        for (int off = 1; off < 16; off <<= 1) {
            const float ov = __shfl_xor(bv[r], off);
            const int oi = __shfl_xor(bi[r], off);
            if (ov > bv[r] || (ov == bv[r] && oi < bi[r])) { bv[r] = ov; bi[r] = oi; }
        }
        if (ln == 0) {
            const int row = m0 + qd * 4 + r;
            lbv[row * 2 + h] = bv[r];
            lbi[row * 2 + h] = bi[r];
        }
    }
    __syncthreads();
    // combine the two code halves per row
    if (t < kBM) {
        const float v0 = lbv[t * 2], v1 = lbv[t * 2 + 1];
        const int i0 = lbi[t * 2], i1 = lbi[t * 2 + 1];
        const int win = (v1 > v0 || (v1 == v0 && i1 < i0)) ? i1 : i0;
        lidx[t] = win;
        atomicAdd(&lhist[win], 1u);
    }
    __syncthreads();

    // epilogue: x re-read coalesced (L2/L3-hot), gather raw codebook row (whole wave shares one
    // row per iter -> coalesced 1 KB), write quantized_, accumulate loss
    float lsum = 0.0f;
    {
        const float* xg = x + (size_t)row0 * kD;
        float* og = out + (size_t)row0 * kD;
        #pragma unroll
        for (int i = 0; i < 8; ++i) {
            const int g = t * 4 + i * 2048;
            const int r = g >> 8;
            const float4 xv = *(const float4*)(xg + g);
            const int idx = lidx[r];
            const float4 q = *(const float4*)(emb + (size_t)idx * kD + (g & 255));
            const float d0 = xv.x - q.x, d1 = xv.y - q.y, d2 = xv.z - q.z, d3 = xv.w - q.w;
            lsum += d0 * d0 + d1 * d1 + d2 * d2 + d3 * d3;
            float4 o;  // ((x + (q-x)) + q) / 2
            o.x = ((xv.x + (q.x - xv.x)) + q.x) * 0.5f;
            o.y = ((xv.y + (q.y - xv.y)) + q.y) * 0.5f;
            o.z = ((xv.z + (q.z - xv.z)) + q.z) * 0.5f;
            o.w = ((xv.w + (q.w - xv.w)) + q.w) * 0.5f;
            *(float4*)&og[g] = o;
        }
    }
    #pragma unroll
    for (int off = 32; off > 0; off >>= 1) lsum += __shfl_xor(lsum, off);
    if (lane == 0) lred[wave] = lsum;
    __syncthreads();
    if (t == 0) {
        float bs = 0.f;
        #pragma unroll
        for (int w = 0; w < 8; ++w) bs += lred[w];
        atomicAdd(loss_accum, bs);
    }

    // flush histogram (skip zero bins)
    const unsigned int h0 = lhist[t];
    if (h0) atomicAdd(&hist[t], h0);
}

// ---------------- final: scalars ----------------
__global__ void vq_final(const unsigned int* __restrict__ hist,
                         const float* __restrict__ loss_accum,
                         float* __restrict__ out) {
    const int t = threadIdx.x;  // 256 threads
    __shared__ float sr[4];
    float s = 0.0f;
    for (int b = t; b < kM; b += 256) {
        const float p = (float)hist[b] * (1.0f / 65536.0f);
        s += p * logf(p + 1e-10f);
    }
    #pragma unroll
    for (int off = 32; off > 0; off >>= 1) s += __shfl_xor(s, off);
    if ((t & 63) == 0) sr[t >> 6] = s;
    __syncthreads();
    if (t == 0) {
        const float tot = sr[0] + sr[1] + sr[2] + sr[3];
        out[16777217] = expf(-tot);                           // perplexity
        out[16777216] = loss_accum[0] * (1.0f / 16777216.0f); // commitment loss
    }
}

extern "C" void kernel_launch(void* const* d_in, const int* in_sizes, int n_in,
                              void* d_out, int out_size, void* d_ws, size_t ws_size,
                              hipStream_t stream) {
    const float* x = (const float*)d_in[0];     // (16,4096,256) fp32
    const float* emb = (const float*)d_in[1];   // (512,256) fp32
    char* ws = (char*)d_ws;
    _Float16* bswz = (_Float16*)ws;                           // 512*256*2 = 262144 B
    float* bias = (float*)(ws + 262144);                      // 2048 B
    unsigned int* hist = (unsigned int*)(ws + 262144 + 2048); // 2048 B
    float* loss = (float*)(ws + 262144 + 4096);               // 4 B
    float* out = (float*)d_out;

    vq_prep<<<kM, 64, 0, stream>>>(emb, bswz, bias, hist, loss);
    vq_main<<<kRows / kBM, 512, 0, stream>>>(x, emb, bswz, bias, hist, loss, out);
    vq_final<<<1, 256, 0, stream>>>(hist, loss, out);
}